// Round 2
// baseline (2456.547 us; speedup 1.0000x reference)
//
#include <hip/hip_runtime.h>
#include <cstdint>
#include <cstddef>

#define NTOK   16
#define MSTEPS 12
#define HID    128
#define INSZ   32

struct KeyArr { uint32_t k0[MSTEPS]; uint32_t k1[MSTEPS]; };

__host__ __device__ static inline uint32_t rotl32(uint32_t x, uint32_t d) {
  return (x << d) | (x >> (32u - d));
}

// Exact replica of JAX's threefry2x32 block cipher (jax/_src/prng.py).
__host__ __device__ static inline void tf2x32(uint32_t k0, uint32_t k1,
                                              uint32_t x0, uint32_t x1,
                                              uint32_t &o0, uint32_t &o1) {
  const uint32_t ks2 = k0 ^ k1 ^ 0x1BD11BDAu;
  x0 += k0; x1 += k1;
  // block 1: rotations A {13,15,26,6}
  x0 += x1; x1 = rotl32(x1, 13); x1 ^= x0;
  x0 += x1; x1 = rotl32(x1, 15); x1 ^= x0;
  x0 += x1; x1 = rotl32(x1, 26); x1 ^= x0;
  x0 += x1; x1 = rotl32(x1,  6); x1 ^= x0;
  x0 += k1; x1 += ks2 + 1u;
  // block 2: rotations B {17,29,16,24}
  x0 += x1; x1 = rotl32(x1, 17); x1 ^= x0;
  x0 += x1; x1 = rotl32(x1, 29); x1 ^= x0;
  x0 += x1; x1 = rotl32(x1, 16); x1 ^= x0;
  x0 += x1; x1 = rotl32(x1, 24); x1 ^= x0;
  x0 += ks2; x1 += k0 + 2u;
  // block 3: A
  x0 += x1; x1 = rotl32(x1, 13); x1 ^= x0;
  x0 += x1; x1 = rotl32(x1, 15); x1 ^= x0;
  x0 += x1; x1 = rotl32(x1, 26); x1 ^= x0;
  x0 += x1; x1 = rotl32(x1,  6); x1 ^= x0;
  x0 += k0; x1 += k1 + 3u;
  // block 4: B
  x0 += x1; x1 = rotl32(x1, 17); x1 ^= x0;
  x0 += x1; x1 = rotl32(x1, 29); x1 ^= x0;
  x0 += x1; x1 = rotl32(x1, 16); x1 ^= x0;
  x0 += x1; x1 = rotl32(x1, 24); x1 ^= x0;
  x0 += k1; x1 += ks2 + 4u;
  // block 5: A
  x0 += x1; x1 = rotl32(x1, 13); x1 ^= x0;
  x0 += x1; x1 = rotl32(x1, 15); x1 ^= x0;
  x0 += x1; x1 = rotl32(x1, 26); x1 ^= x0;
  x0 += x1; x1 = rotl32(x1,  6); x1 ^= x0;
  x0 += ks2; x1 += k0 + 5u;
  o0 = x0; o1 = x1;
}

// One wave (64 lanes) per sequence, 4 waves per block. Wh staged in LDS,
// shared across the 4 waves. Lane owns hidden columns 2*lane, 2*lane+1.
__global__ __launch_bounds__(256)
void eq_sampler(const float* __restrict__ x0in, const float* __restrict__ h0in,
                const float* __restrict__ Wx,   const float* __restrict__ Wh,
                const float* __restrict__ bvec, const float* __restrict__ Wp,
                const float* __restrict__ bp,   float* __restrict__ out,
                int n, KeyArr keys)
{
  __shared__ float whs[HID * HID];      // 64 KB
  __shared__ float hbuf[4][HID];        // per-wave h broadcast buffer
  __shared__ int   seqs[4][MSTEPS];

  const int tid  = threadIdx.x;
  const int lane = tid & 63;
  const int wv   = tid >> 6;
  const int gseq = blockIdx.x * 4 + wv;
  const bool valid = gseq < n;

  // stage Wh -> LDS (row-major, same layout as global)
  for (int i = tid; i < HID * HID / 4; i += 256)
    ((float4*)whs)[i] = ((const float4*)Wh)[i];
  if (lane < MSTEPS) seqs[wv][lane] = -1;
  __syncthreads();

  const int j0 = 2 * lane, j1 = 2 * lane + 1;
  float hl0 = h0in[j0], hl1 = h0in[j1];
  int  cnt = 1, ln = 0, lengths = 1;
  bool act = true, hasvar = false;
  int  ps0 = -1, ps1 = -1;

  float* o_seq = out;
  float* o_ent = out + (size_t)n * 12;
  float* o_lp  = out + (size_t)n * 24;
  float* o_cnt = out + (size_t)n * 36;
  float* o_len = out + (size_t)n * 37;
  float* o_msk = out + (size_t)n * 38;

  if (valid && lane == 0) o_msk[(size_t)gseq * 13] = 1.0f;

  const float TINY = 1.17549435e-38f;

  for (int t = 0; t < MSTEPS; ++t) {
    // publish current h for this wave
    *(float2*)&hbuf[wv][j0] = make_float2(hl0, hl1);
    __syncthreads();

    // x @ Wx  (dense at t==0; one-hot(ps0)++one-hot(ps1) afterwards)
    float s10, s11;
    if (t == 0) {
      s10 = 0.f; s11 = 0.f;
      for (int k = 0; k < INSZ; ++k) {
        float xv = x0in[k];
        s10 = fmaf(xv, Wx[k * HID + j0], s10);
        s11 = fmaf(xv, Wx[k * HID + j1], s11);
      }
    } else {
      float a0 = 0.f, a1 = 0.f, c0v = 0.f, c1v = 0.f;
      if (ps0 >= 0) { a0  = Wx[ps0 * HID + j0];          a1  = Wx[ps0 * HID + j1]; }
      if (ps1 >= 0) { c0v = Wx[(NTOK + ps1) * HID + j0]; c1v = Wx[(NTOK + ps1) * HID + j1]; }
      s10 = a0 + c0v; s11 = a1 + c1v;
    }

    // h @ Wh
    float s20 = 0.f, s21 = 0.f;
    #pragma unroll 8
    for (int i = 0; i < HID; ++i) {
      float hv = hbuf[wv][i];
      float2 w = *(const float2*)&whs[i * HID + j0];
      s20 = fmaf(hv, w.x, s20);
      s21 = fmaf(hv, w.y, s21);
    }
    float2 bb = *(const float2*)&bvec[j0];
    float hn0 = tanhf((s10 + s20) + bb.x);
    float hn1 = tanhf((s11 + s21) + bb.y);
    __syncthreads();
    *(float2*)&hbuf[wv][j0] = make_float2(hn0, hn1);
    __syncthreads();

    int tok = 0; float entv = 0.f, lpw = 0.f;
    if (lane < NTOK) {
      // logits = hnew @ Wp + bp
      float s = 0.f;
      #pragma unroll 8
      for (int i = 0; i < HID; ++i)
        s = fmaf(hbuf[wv][i], Wp[i * NTOK + lane], s);
      float logit = s + bp[lane];

      // softmax across the 16-lane group
      float m = logit;
      for (int msk = 1; msk < 16; msk <<= 1) m = fmaxf(m, __shfl_xor(m, msk, 16));
      float e = expf(logit - m);
      float Z = e;
      for (int msk = 1; msk < 16; msk <<= 1) Z += __shfl_xor(Z, msk, 16);
      float pr = e / Z;

      // constraints (zero out masked tokens)
      int cl = cnt + ln;
      if (lane >= 8 && cl < 2)                pr = 0.f;  // too short for 0-arity
      if (lane <  8 && cl > MSTEPS - 2)       pr = 0.f;  // too long for >=1-arity
      if (lane == 8 && cnt == 1 && !hasvar)   pr = 0.f;  // last slot must allow a var

      float S = pr;
      for (int msk = 1; msk < 16; msk <<= 1) S += __shfl_xor(S, msk, 16);
      float p = pr / S;
      bool pos = p > 0.f;
      float lgp = pos ? logf(p) : -__builtin_inff();

      // Gumbel noise: JAX threefry PARTITIONABLE schedule — per element e of
      // the (n,16) draw, bits = b1^b2 of cipher(step_key, (0, e)).
      uint32_t eidx = (uint32_t)gseq * 16u + (uint32_t)lane;
      uint32_t b1, b2;
      tf2x32(keys.k0[t], keys.k1[t], 0u, eidx, b1, b2);
      uint32_t bits = b1 ^ b2;
      float uf = __uint_as_float((bits >> 9) | 0x3F800000u) - 1.0f;
      uf += TINY;                 // floats*(1-tiny)+tiny: *(1.0) exact, +tiny
      uf = fmaxf(TINY, uf);
      float g = -logf(-logf(uf));
      float score = lgp + g;      // -inf stays -inf

      // argmax, ties -> lowest index (jnp.argmax semantics)
      float bsv = score; int bji = lane;
      for (int msk = 1; msk < 16; msk <<= 1) {
        float ov = __shfl_xor(bsv, msk, 16);
        int   oi = __shfl_xor(bji, msk, 16);
        if (ov > bsv || (ov == bsv && oi < bji)) { bsv = ov; bji = oi; }
      }

      // entropy = -sum p*log(p) over p>0
      float es = pos ? p * lgp : 0.f;
      for (int msk = 1; msk < 16; msk <<= 1) es += __shfl_xor(es, msk, 16);
      entv = -es;
      lpw  = __shfl(lgp, bji, 16);
      tok  = bji;
    }
    // broadcast winner to the whole wave
    tok  = __shfl(tok,  0, 64);
    entv = __shfl(entv, 0, 64);
    lpw  = __shfl(lpw,  0, 64);

    cnt += -1 + ((tok < 4) ? 2 : (tok < 8 ? 1 : 0));
    ln  += 1;
    act  = (cnt > 0) && act;
    if (tok >= 9) hasvar = true;
    lengths += act ? 1 : 0;

    if (lane == 0) {
      seqs[wv][t] = tok;
      if (valid) {
        o_ent[(size_t)gseq * 12 + t] = entv;
        o_lp [(size_t)gseq * 12 + t] = lpw;
        o_msk[(size_t)gseq * 13 + t + 1] = act ? 1.f : 0.f;
      }
    }
    __syncthreads();

    // parent & sibling (reference _parent_sibling semantics)
    if (tok < 8) { ps0 = tok; ps1 = -1; }
    else {
      float c = 0.f; int p0 = -1, p1 = -1;
      for (int i = t; i >= 0; --i) {
        int tk = seqs[wv][i];
        float ar = (tk >= 0 && tk < 4) ? 2.f : ((tk >= 4 && tk < 8) ? 1.f : 0.f);
        c += ar - 1.f;
        if (c == 0.f && p0 == -1) {
          p0 = tk;
          p1 = (i + 1 < MSTEPS) ? seqs[wv][i + 1] : -1;
        }
      }
      ps0 = p0; ps1 = p1;
    }

    hl0 = hn0; hl1 = hn1;
  }

  if (valid) {
    if (lane == 0) {
      o_cnt[gseq] = (float)cnt;
      o_len[gseq] = (float)lengths;
    }
    if (lane < MSTEPS)
      o_seq[(size_t)gseq * 12 + lane] = (float)seqs[wv][lane];
  }
}

extern "C" void kernel_launch(void* const* d_in, const int* in_sizes, int n_in,
                              void* d_out, int out_size, void* d_ws, size_t ws_size,
                              hipStream_t stream) {
  const float* x0 = (const float*)d_in[1];
  const float* h0 = (const float*)d_in[2];
  const float* Wx = (const float*)d_in[3];
  const float* Wh = (const float*)d_in[4];
  const float* bv = (const float*)d_in[5];
  const float* Wp = (const float*)d_in[6];
  const float* bp = (const float*)d_in[7];
  float* out = (float*)d_out;

  int n = out_size / 51;   // 12+12+12+1+1+13 floats per sequence

  // jax.random.split(jax.random.key(42), 12) under jax_threefry_partitionable
  // (default since JAX 0.4.36): keys[t] = threefry((0,42), (0, t)).
  KeyArr ka;
  for (int t = 0; t < 12; ++t) {
    uint32_t o0, o1;
    tf2x32(0u, 42u, 0u, (uint32_t)t, o0, o1);
    ka.k0[t] = o0; ka.k1[t] = o1;
  }

  int blocks = (n + 3) / 4;
  eq_sampler<<<blocks, 256, 0, stream>>>(x0, h0, Wx, Wh, bv, Wp, bp, out, n, ka);
}

// Round 3
// 564.785 us; speedup vs baseline: 4.3495x; 4.3495x over previous
//
#include <hip/hip_runtime.h>
#include <cstdint>
#include <cstddef>

#define NTOK   16
#define MSTEPS 12
#define HID    128
#define INSZ   32
#define SPB    64     // sequences per block
#define TPB    128    // threads per block (2 waves)

struct KeyArr { uint32_t k0[MSTEPS]; uint32_t k1[MSTEPS]; };

__host__ __device__ static inline uint32_t rotl32(uint32_t x, uint32_t d) {
  return (x << d) | (x >> (32u - d));
}

// Exact replica of JAX's threefry2x32 block cipher.
__host__ __device__ static inline void tf2x32(uint32_t k0, uint32_t k1,
                                              uint32_t x0, uint32_t x1,
                                              uint32_t &o0, uint32_t &o1) {
  const uint32_t ks2 = k0 ^ k1 ^ 0x1BD11BDAu;
  x0 += k0; x1 += k1;
  x0 += x1; x1 = rotl32(x1, 13); x1 ^= x0;
  x0 += x1; x1 = rotl32(x1, 15); x1 ^= x0;
  x0 += x1; x1 = rotl32(x1, 26); x1 ^= x0;
  x0 += x1; x1 = rotl32(x1,  6); x1 ^= x0;
  x0 += k1; x1 += ks2 + 1u;
  x0 += x1; x1 = rotl32(x1, 17); x1 ^= x0;
  x0 += x1; x1 = rotl32(x1, 29); x1 ^= x0;
  x0 += x1; x1 = rotl32(x1, 16); x1 ^= x0;
  x0 += x1; x1 = rotl32(x1, 24); x1 ^= x0;
  x0 += ks2; x1 += k0 + 2u;
  x0 += x1; x1 = rotl32(x1, 13); x1 ^= x0;
  x0 += x1; x1 = rotl32(x1, 15); x1 ^= x0;
  x0 += x1; x1 = rotl32(x1, 26); x1 ^= x0;
  x0 += x1; x1 = rotl32(x1,  6); x1 ^= x0;
  x0 += k0; x1 += k1 + 3u;
  x0 += x1; x1 = rotl32(x1, 17); x1 ^= x0;
  x0 += x1; x1 = rotl32(x1, 29); x1 ^= x0;
  x0 += x1; x1 = rotl32(x1, 16); x1 ^= x0;
  x0 += x1; x1 = rotl32(x1, 24); x1 ^= x0;
  x0 += k1; x1 += ks2 + 4u;
  x0 += x1; x1 = rotl32(x1, 13); x1 ^= x0;
  x0 += x1; x1 = rotl32(x1, 15); x1 ^= x0;
  x0 += x1; x1 = rotl32(x1, 26); x1 ^= x0;
  x0 += x1; x1 = rotl32(x1,  6); x1 ^= x0;
  x0 += ks2; x1 += k0 + 5u;
  o0 = x0; o1 = x1;
}

// Swizzled LDS address for h[k][s] (row = k 0..127, s 0..63, 16B-chunk XOR):
// chunk' = (s>>2) ^ ((k>>3)&15). Keeps b128 alignment; GEMM row-reads are
// conflict-free broadcasts, column-major Hnew writes spread across banks.
__device__ __forceinline__ int haddr(int k, int s) {
  return k * SPB + ((((s >> 2) ^ ((k >> 3) & 15)) << 2) | (s & 3));
}

__global__ __launch_bounds__(TPB)
void eq_sampler(const float* __restrict__ x0in, const float* __restrict__ h0in,
                const float* __restrict__ Wx,   const float* __restrict__ Wh,
                const float* __restrict__ bvec, const float* __restrict__ Wp,
                const float* __restrict__ bp,   float* __restrict__ out,
                int n, KeyArr keys)
{
  __shared__ float hsw[HID * SPB];        // 32 KB swizzled h[k][s]
  __shared__ float xw0[HID];              // t=0 dense x0@Wx (same for all seqs)
  __shared__ int   seqtok[SPB][MSTEPS];
  __shared__ int   cnt_s[SPB];
  __shared__ int   hv_s[SPB];             // hasvar
  __shared__ int   ps0_s[SPB], ps1_s[SPB];

  const int tid   = threadIdx.x;
  const int sg    = tid >> 4,  cg = tid & 15;     // GEMM tile coords
  const int srow  = sg * 8,    cbase = cg * 8;    // 8 seqs x 8 cols per thread
  const int seq   = tid >> 1,  th = tid & 1;      // sampling coords
  const int gbase = blockIdx.x * SPB;
  const float TINY = 1.17549435e-38f;

  // ---- init: xw0, h0 broadcast, per-seq state ----
  {
    float s = 0.f;
    for (int k = 0; k < INSZ; ++k) s = fmaf(x0in[k], Wx[k * HID + tid], s);
    xw0[tid] = s;
    float v = h0in[tid];
    for (int s2 = 0; s2 < SPB; ++s2) hsw[haddr(tid, s2)] = v;
    if (tid < SPB) {
      cnt_s[tid] = 1; hv_s[tid] = 0; ps0_s[tid] = -1; ps1_s[tid] = -1;
      for (int j = 0; j < MSTEPS; ++j) seqtok[tid][j] = -1;
    }
  }

  float bb[8], bpv[8];
  #pragma unroll
  for (int c = 0; c < 8; ++c) bb[c] = bvec[cbase + c];
  #pragma unroll
  for (int j = 0; j < 8; ++j) bpv[j] = bp[th * 8 + j];

  bool act = true; int lengths = 1;

  float* o_seq = out;
  float* o_ent = out + (size_t)n * 12;
  float* o_lp  = out + (size_t)n * 24;
  float* o_cnt = out + (size_t)n * 36;
  float* o_len = out + (size_t)n * 37;
  float* o_msk = out + (size_t)n * 38;

  if (th == 0 && gbase + seq < n) o_msk[(size_t)(gbase + seq) * 13] = 1.0f;
  __syncthreads();

  for (int t = 0; t < MSTEPS; ++t) {
    // ---- phase 1: H @ Wh, 8x8 register tile, Wh from global (L1/L2) ----
    float acc[8][8];
    #pragma unroll
    for (int s = 0; s < 8; ++s)
      #pragma unroll
      for (int c = 0; c < 8; ++c) acc[s][c] = 0.f;

    const float* whp = Wh + cbase;
    #pragma unroll 2
    for (int k = 0; k < HID; ++k) {
      float4 w0 = *(const float4*)(whp + k * HID);
      float4 w1 = *(const float4*)(whp + k * HID + 4);
      float4 ha = *(const float4*)&hsw[haddr(k, srow)];
      float4 hb = *(const float4*)&hsw[haddr(k, srow + 4)];
      float wv[8] = {w0.x, w0.y, w0.z, w0.w, w1.x, w1.y, w1.z, w1.w};
      float hv[8] = {ha.x, ha.y, ha.z, ha.w, hb.x, hb.y, hb.z, hb.w};
      #pragma unroll
      for (int s = 0; s < 8; ++s)
        #pragma unroll
        for (int c = 0; c < 8; ++c)
          acc[s][c] = fmaf(hv[s], wv[c], acc[s][c]);
    }

    // epilogue: z = (xw + acc) + b; h_new = tanh(z)  (order matches passing kernel)
    #pragma unroll
    for (int s = 0; s < 8; ++s) {
      const int sq = srow + s;
      float xw[8];
      if (t == 0) {
        #pragma unroll
        for (int c = 0; c < 8; ++c) xw[c] = xw0[cbase + c];
      } else {
        const int p0 = ps0_s[sq], p1 = ps1_s[sq];
        float av[8], cv[8];
        #pragma unroll
        for (int c = 0; c < 8; ++c) { av[c] = 0.f; cv[c] = 0.f; }
        if (p0 >= 0) {
          float4 u0 = *(const float4*)&Wx[p0 * HID + cbase];
          float4 u1 = *(const float4*)&Wx[p0 * HID + cbase + 4];
          av[0]=u0.x; av[1]=u0.y; av[2]=u0.z; av[3]=u0.w;
          av[4]=u1.x; av[5]=u1.y; av[6]=u1.z; av[7]=u1.w;
        }
        if (p1 >= 0) {
          float4 u0 = *(const float4*)&Wx[(NTOK + p1) * HID + cbase];
          float4 u1 = *(const float4*)&Wx[(NTOK + p1) * HID + cbase + 4];
          cv[0]=u0.x; cv[1]=u0.y; cv[2]=u0.z; cv[3]=u0.w;
          cv[4]=u1.x; cv[5]=u1.y; cv[6]=u1.z; cv[7]=u1.w;
        }
        #pragma unroll
        for (int c = 0; c < 8; ++c) xw[c] = av[c] + cv[c];
      }
      #pragma unroll
      for (int c = 0; c < 8; ++c)
        acc[s][c] = tanhf((xw[c] + acc[s][c]) + bb[c]);
    }

    __syncthreads();   // all reads of old h complete
    #pragma unroll
    for (int c = 0; c < 8; ++c) {
      const int col = cbase + c;
      *(float4*)&hsw[haddr(col, srow)] =
          make_float4(acc[0][c], acc[1][c], acc[2][c], acc[3][c]);
      *(float4*)&hsw[haddr(col, srow + 4)] =
          make_float4(acc[4][c], acc[5][c], acc[6][c], acc[7][c]);
    }
    __syncthreads();   // new h visible

    // ---- phase 2: logits for (seq, 8 tokens), Wp from global (L1) ----
    float lg[8];
    #pragma unroll
    for (int j = 0; j < 8; ++j) lg[j] = 0.f;
    const float* wpp = Wp + th * 8;
    #pragma unroll 4
    for (int k = 0; k < HID; ++k) {
      float hvv = hsw[haddr(k, seq)];
      float4 p0 = *(const float4*)(wpp + k * NTOK);
      float4 p1 = *(const float4*)(wpp + k * NTOK + 4);
      lg[0] = fmaf(hvv, p0.x, lg[0]); lg[1] = fmaf(hvv, p0.y, lg[1]);
      lg[2] = fmaf(hvv, p0.z, lg[2]); lg[3] = fmaf(hvv, p0.w, lg[3]);
      lg[4] = fmaf(hvv, p1.x, lg[4]); lg[5] = fmaf(hvv, p1.y, lg[5]);
      lg[6] = fmaf(hvv, p1.z, lg[6]); lg[7] = fmaf(hvv, p1.w, lg[7]);
    }
    #pragma unroll
    for (int j = 0; j < 8; ++j) lg[j] += bpv[j];

    // ---- phase 3: softmax + constraints + gumbel argmax (pair of threads) ----
    float m8 = lg[0];
    #pragma unroll
    for (int j = 1; j < 8; ++j) m8 = fmaxf(m8, lg[j]);
    float mm = fmaxf(m8, __shfl_xor(m8, 1));

    float e[8]; float Zp = 0.f;
    #pragma unroll
    for (int j = 0; j < 8; ++j) { e[j] = expf(lg[j] - mm); Zp += e[j]; }
    float Z = Zp + __shfl_xor(Zp, 1);

    const int cntv = cnt_s[seq];
    const int cl   = cntv + t;
    const int hasv = hv_s[seq];

    float pr[8]; float Sp = 0.f;
    #pragma unroll
    for (int j = 0; j < 8; ++j) {
      const int tj = th * 8 + j;
      float p = e[j] / Z;
      if (tj >= 8 && cl < 2)                  p = 0.f;
      if (tj <  8 && cl > MSTEPS - 2)         p = 0.f;
      if (tj == 8 && cntv == 1 && !hasv)      p = 0.f;
      pr[j] = p; Sp += p;
    }
    float S = Sp + __shfl_xor(Sp, 1);

    float bs = 0.f, blp = 0.f, ep = 0.f; int bj = 0;
    #pragma unroll
    for (int j = 0; j < 8; ++j) {
      const int tj = th * 8 + j;
      float p = pr[j] / S;
      bool pos = p > 0.f;
      float lgpj = pos ? logf(p) : -__builtin_inff();
      ep += pos ? p * lgpj : 0.f;
      uint32_t eidx = (uint32_t)(gbase + seq) * 16u + (uint32_t)tj;
      uint32_t b1, b2;
      tf2x32(keys.k0[t], keys.k1[t], 0u, eidx, b1, b2);
      uint32_t bits = b1 ^ b2;
      float uf = __uint_as_float((bits >> 9) | 0x3F800000u) - 1.0f;
      uf += TINY; uf = fmaxf(TINY, uf);
      float g = -logf(-logf(uf));
      float sc = lgpj + g;
      if (j == 0) { bs = sc; bj = tj; blp = lgpj; }
      else if (sc > bs) { bs = sc; bj = tj; blp = lgpj; }
    }
    {
      float obs  = __shfl_xor(bs, 1);
      int   obj  = __shfl_xor(bj, 1);
      float oblp = __shfl_xor(blp, 1);
      if (obs > bs || (obs == bs && obj < bj)) { bs = obs; bj = obj; blp = oblp; }
    }
    float ent = -(ep + __shfl_xor(ep, 1));
    const int tok = bj;

    if (th == 0) {
      int c2 = cntv - 1 + (tok < 4 ? 2 : (tok < 8 ? 1 : 0));
      act = act && (c2 > 0);
      lengths += act ? 1 : 0;
      cnt_s[seq] = c2;
      if (tok >= 9) hv_s[seq] = 1;
      seqtok[seq][t] = tok;
      const int gseq = gbase + seq;
      if (gseq < n) {
        o_ent[(size_t)gseq * 12 + t] = ent;
        o_lp [(size_t)gseq * 12 + t] = blp;
        o_msk[(size_t)gseq * 13 + t + 1] = act ? 1.f : 0.f;
      }
      if (tok < 8) { ps0_s[seq] = tok; ps1_s[seq] = -1; }
      else {
        float c = 0.f; int p0 = -1, p1v = -1;
        for (int i = t; i >= 0; --i) {
          int tk = seqtok[seq][i];
          float ar = (tk >= 0 && tk < 4) ? 2.f : ((tk >= 4 && tk < 8) ? 1.f : 0.f);
          c += ar - 1.f;
          if (c == 0.f && p0 == -1) {
            p0 = tk; p1v = (i + 1 < MSTEPS) ? seqtok[seq][i + 1] : -1;
          }
        }
        ps0_s[seq] = p0; ps1_s[seq] = p1v;
      }
    }
    __syncthreads();   // per-seq state ready for next step
  }

  if (th == 0) {
    const int gseq = gbase + seq;
    if (gseq < n) {
      o_cnt[gseq] = (float)cnt_s[seq];
      o_len[gseq] = (float)lengths;
      for (int j = 0; j < MSTEPS; ++j)
        o_seq[(size_t)gseq * 12 + j] = (float)seqtok[seq][j];
    }
  }
}

extern "C" void kernel_launch(void* const* d_in, const int* in_sizes, int n_in,
                              void* d_out, int out_size, void* d_ws, size_t ws_size,
                              hipStream_t stream) {
  const float* x0 = (const float*)d_in[1];
  const float* h0 = (const float*)d_in[2];
  const float* Wx = (const float*)d_in[3];
  const float* Wh = (const float*)d_in[4];
  const float* bv = (const float*)d_in[5];
  const float* Wp = (const float*)d_in[6];
  const float* bp = (const float*)d_in[7];
  float* out = (float*)d_out;

  int n = out_size / 51;   // 12+12+12+1+1+13 floats per sequence

  // jax.random.split(jax.random.key(42), 12), partitionable threefry:
  // keys[t] = threefry((0,42), (0, t)).
  KeyArr ka;
  for (int t = 0; t < 12; ++t) {
    uint32_t o0, o1;
    tf2x32(0u, 42u, 0u, (uint32_t)t, o0, o1);
    ka.k0[t] = o0; ka.k1[t] = o1;
  }

  int blocks = (n + SPB - 1) / SPB;
  eq_sampler<<<blocks, TPB, 0, stream>>>(x0, h0, Wx, Wh, bv, Wp, bp, out, n, ka);
}